// Round 5
// baseline (286.302 us; speedup 1.0000x reference)
//
#include <hip/hip_runtime.h>
#include <math.h>

#define S_TOK 2048
#define H_DIM 1024
#define E_NUM 16
#define FF_DIM 1024
#define TOPK 4
#define CLIPV 7.0f
#define AUXC 0.02f
#define BK 32
#define NT (H_DIM / BK)

typedef short bf16x8 __attribute__((ext_vector_type(8)));
typedef float f32x4 __attribute__((ext_vector_type(4)));

__device__ __forceinline__ unsigned short f2bf(float f) {
  unsigned int u = __float_as_uint(f);
  u += 0x7fffu + ((u >> 16) & 1u);
  return (unsigned short)(u >> 16);
}

__device__ __forceinline__ void gload16(const void* g, void* l) {
  __builtin_amdgcn_global_load_lds((const __attribute__((address_space(1))) void*)g,
                                   (__attribute__((address_space(3))) void*)l, 16, 0, 0);
}

__device__ __forceinline__ int imin(int a, int b) { return a < b ? a : b; }

// ---------------- router logits + x->bf16 convert: one wave per token ----------------
__global__ void logits_kernel(const float* __restrict__ x, const float* __restrict__ rw,
                              const float* __restrict__ rb, float* __restrict__ logits,
                              unsigned short* __restrict__ xb) {
  int tok = blockIdx.x * 4 + (threadIdx.x >> 6);
  int lane = threadIdx.x & 63;
  const float4* xr = (const float4*)(x + (size_t)tok * H_DIM);
  ushort4* xbw = (ushort4*)(xb + (size_t)tok * H_DIM);
  float p[E_NUM];
#pragma unroll
  for (int e = 0; e < E_NUM; ++e) p[e] = 0.f;
#pragma unroll
  for (int it = 0; it < 4; ++it) {
    float4 xv = xr[it * 64 + lane];
    ushort4 o;
    o.x = f2bf(xv.x); o.y = f2bf(xv.y); o.z = f2bf(xv.z); o.w = f2bf(xv.w);
    xbw[it * 64 + lane] = o;
#pragma unroll
    for (int e = 0; e < E_NUM; ++e) {
      float4 wv = ((const float4*)(rw + (size_t)e * H_DIM))[it * 64 + lane];
      p[e] += xv.x * wv.x + xv.y * wv.y + xv.z * wv.z + xv.w * wv.w;
    }
  }
#pragma unroll
  for (int e = 0; e < E_NUM; ++e) {
#pragma unroll
    for (int off = 32; off > 0; off >>= 1) p[e] += __shfl_xor(p[e], off);
  }
  if (lane == 0) {
    float4* lp = (float4*)&logits[tok * E_NUM];
#pragma unroll
    for (int q = 0; q < 4; ++q)
      lp[q] = make_float4(p[q * 4 + 0] + rb[q * 4 + 0], p[q * 4 + 1] + rb[q * 4 + 1],
                          p[q * 4 + 2] + rb[q * 4 + 2], p[q * 4 + 3] + rb[q * 4 + 3]);
  }
}

// ---------------- top-k + aux stats ----------------
__global__ __launch_bounds__(256) void topk_kernel(const float* __restrict__ logits,
                                                   int* __restrict__ topk_i, float* __restrict__ topk_w,
                                                   int* __restrict__ counts, float* __restrict__ imp,
                                                   int* __restrict__ pos_cnt) {
  __shared__ float s_imp[E_NUM];
  __shared__ int s_cnt[E_NUM];
  __shared__ int s_pos[TOPK];
  int tid = threadIdx.x;
  if (tid < E_NUM) { s_imp[tid] = 0.f; s_cnt[tid] = 0; }
  if (tid < TOPK) s_pos[tid] = 0;
  __syncthreads();

  int t = blockIdx.x * 256 + tid;
  float lg[E_NUM];
  {
    const float4* lp = (const float4*)&logits[t * E_NUM];
#pragma unroll
    for (int q = 0; q < 4; ++q) {
      float4 v = lp[q];
      lg[q * 4 + 0] = v.x; lg[q * 4 + 1] = v.y; lg[q * 4 + 2] = v.z; lg[q * 4 + 3] = v.w;
    }
  }
  int idx[TOPK]; float val[TOPK];
  float tmp[E_NUM];
#pragma unroll
  for (int e = 0; e < E_NUM; ++e) tmp[e] = lg[e];
#pragma unroll
  for (int k = 0; k < TOPK; ++k) {
    float best = -INFINITY; int bi = 0;
#pragma unroll
    for (int e = 0; e < E_NUM; ++e) if (tmp[e] > best) { best = tmp[e]; bi = e; }
    val[k] = best; idx[k] = bi; tmp[bi] = -INFINITY;
  }
  float ssum = 0.f, wv[TOPK];
#pragma unroll
  for (int k = 0; k < TOPK; ++k) { wv[k] = expf(val[k] - val[0]); ssum += wv[k]; }
#pragma unroll
  for (int k = 0; k < TOPK; ++k) wv[k] /= ssum;
#pragma unroll
  for (int k = 0; k < TOPK; ++k) {
    topk_i[t * TOPK + k] = idx[k];
    topk_w[t * TOPK + k] = wv[k];
  }
  float se = 0.f, pr[E_NUM];
#pragma unroll
  for (int e = 0; e < E_NUM; ++e) { pr[e] = expf(lg[e] - val[0]); se += pr[e]; }
  float inv = 1.f / se;
  int mi = idx[0], pos = 0;
#pragma unroll
  for (int k = 1; k < TOPK; ++k) if (idx[k] > mi) { mi = idx[k]; pos = k; }

  int lane = tid & 63;
#pragma unroll
  for (int e = 0; e < E_NUM; ++e) {
    float v = pr[e] * inv;
    int c = (idx[0] == e) + (idx[1] == e) + (idx[2] == e) + (idx[3] == e);
#pragma unroll
    for (int off = 32; off > 0; off >>= 1) {
      v += __shfl_xor(v, off);
      c += __shfl_xor(c, off);
    }
    if (lane == 0) {
      atomicAdd(&s_imp[e], v);
      atomicAdd(&s_cnt[e], c);
    }
  }
#pragma unroll
  for (int k = 0; k < TOPK; ++k) {
    int pc = (pos == k) ? 1 : 0;
#pragma unroll
    for (int off = 32; off > 0; off >>= 1) pc += __shfl_xor(pc, off);
    if (lane == 0) atomicAdd(&s_pos[k], pc);
  }
  __syncthreads();
  if (tid < E_NUM) {
    atomicAdd(&imp[tid], s_imp[tid]);
    atomicAdd(&counts[tid], s_cnt[tid]);
  }
  if (tid < TOPK) atomicAdd(&pos_cnt[tid], s_pos[tid]);
}

// ---------------- exclusive scan over 16 expert counts ----------------
__global__ void scan_kernel(const int* __restrict__ counts, int* __restrict__ offsets) {
  if (threadIdx.x == 0) {
    int off = 0;
    for (int e = 0; e < E_NUM; ++e) { offsets[e] = off; off += counts[e]; }
    offsets[E_NUM] = off;
  }
}

// ---------------- build grouped token lists ----------------
__global__ __launch_bounds__(256) void assign_kernel(
    const int* __restrict__ topk_i, const float* __restrict__ topk_w,
    const int* __restrict__ offsets, int* __restrict__ cursor,
    int* __restrict__ tok_list, float* __restrict__ w_list) {
  __shared__ int s_cnt[E_NUM];
  __shared__ int s_base[E_NUM];
  int tid = threadIdx.x;
  if (tid < E_NUM) s_cnt[tid] = 0;
  __syncthreads();
  int t = blockIdx.x * 256 + tid;
  int e[TOPK], lslot[TOPK];
#pragma unroll
  for (int k = 0; k < TOPK; ++k) {
    e[k] = topk_i[t * TOPK + k];
    lslot[k] = atomicAdd(&s_cnt[e[k]], 1);
  }
  __syncthreads();
  if (tid < E_NUM) s_base[tid] = atomicAdd(&cursor[tid], s_cnt[tid]);
  __syncthreads();
#pragma unroll
  for (int k = 0; k < TOPK; ++k) {
    int slot = offsets[e[k]] + s_base[e[k]] + lslot[k];
    tok_list[slot] = t;
    w_list[slot] = topk_w[t * TOPK + k];
  }
}

// ---------------- tiled transpose fp32 [R][C] -> bf16 [C][R], per expert slab ----------------
__global__ void transpose_kernel(const float* __restrict__ in, unsigned short* __restrict__ out,
                                 int R, int C) {
  __shared__ float tile[64][65];
  int e = blockIdx.z;
  in  += (size_t)e * R * C;
  out += (size_t)e * R * C;
  int r0 = blockIdx.y * 64, c0 = blockIdx.x * 64;
  int tx = threadIdx.x & 15, ty = threadIdx.x >> 4;
#pragma unroll
  for (int j = 0; j < 4; ++j) {
    int r = ty + j * 16;
    float4 v = *(const float4*)&in[(size_t)(r0 + r) * C + c0 + tx * 4];
    tile[r][tx * 4 + 0] = v.x; tile[r][tx * 4 + 1] = v.y;
    tile[r][tx * 4 + 2] = v.z; tile[r][tx * 4 + 3] = v.w;
  }
  __syncthreads();
#pragma unroll
  for (int j = 0; j < 4; ++j) {
    int c = ty + j * 16;
    ushort4 o;
    o.x = f2bf(tile[tx * 4 + 0][c]);
    o.y = f2bf(tile[tx * 4 + 1][c]);
    o.z = f2bf(tile[tx * 4 + 2][c]);
    o.w = f2bf(tile[tx * 4 + 3][c]);
    *(ushort4*)&out[(size_t)(c0 + c) * R + r0 + tx * 4] = o;
  }
}

// ---------------- GEMM1: BM=128 x BN=256(panel=128 f up/gate), 4 waves, acc[8][4] ----------------
// grid: 2048 blocks 1-D, T1 bijective XCD swizzle (2048%8==0).
// Panel row r -> weight row: f = n0f + (r>>5)*16 + (r&15), type=(r>>4)&1 (0=up,1=gate).
__global__ __launch_bounds__(256, 2) void gemm1_kernel(
    const unsigned short* __restrict__ xb, const unsigned short* __restrict__ winT,
    const float* __restrict__ b_in, const int* __restrict__ offsets,
    const int* __restrict__ tok_list, unsigned short* __restrict__ act) {
  __shared__ unsigned short ldsA[2][128 * BK];
  __shared__ unsigned short ldsB[2][256 * BK];
  const int lin = blockIdx.x;
  const int nid = (lin & 7) * 256 + (lin >> 3);   // XCD-contiguous chunks
  const int e  = nid >> 7;
  const int mt = (nid & 127) >> 3;
  const int nt = nid & 7;
  const int base = offsets[e];
  const int cnt = offsets[e + 1] - base;
  if (mt * 128 >= cnt) return;
  const int n0f = nt * 128;
  const int tid = threadIdx.x, w = tid >> 6, lane = tid & 63;

  // staging: wave w stages A rows [w*16,w*16+16)+{0,64}, B rows +{0,64,128,192}
  const int arow = w * 16 + (lane >> 2);
  const int t0 = tok_list[base + imin(mt * 128 + arow, cnt - 1)];
  const int t1 = tok_list[base + imin(mt * 128 + arow + 64, cnt - 1)];
  const unsigned short* gA0 = xb + (size_t)t0 * H_DIM + (lane & 3) * 8;
  const unsigned short* gA1 = xb + (size_t)t1 * H_DIM + (lane & 3) * 8;
  auto brow_f = [&](int r) {
    int f = n0f + ((r >> 5) << 4) + (r & 15);
    return ((r >> 4) & 1) ? (FF_DIM + f) : f;
  };
  const unsigned short* we = winT + (size_t)e * 2 * FF_DIM * H_DIM;
  const unsigned short* gB0 = we + (size_t)brow_f(arow)       * H_DIM + (lane & 3) * 8;
  const unsigned short* gB1 = we + (size_t)brow_f(arow + 64)  * H_DIM + (lane & 3) * 8;
  const unsigned short* gB2 = we + (size_t)brow_f(arow + 128) * H_DIM + (lane & 3) * 8;
  const unsigned short* gB3 = we + (size_t)brow_f(arow + 192) * H_DIM + (lane & 3) * 8;

  f32x4 acc[8][4];
#pragma unroll
  for (int m = 0; m < 8; ++m)
#pragma unroll
    for (int n = 0; n < 4; ++n) acc[m][n] = (f32x4){0.f, 0.f, 0.f, 0.f};

#define STAGE1(buf, k0)                                     \
  do {                                                      \
    gload16(gA0 + (k0), &ldsA[buf][w * 512]);               \
    gload16(gA1 + (k0), &ldsA[buf][w * 512 + 2048]);        \
    gload16(gB0 + (k0), &ldsB[buf][w * 512]);               \
    gload16(gB1 + (k0), &ldsB[buf][w * 512 + 2048]);        \
    gload16(gB2 + (k0), &ldsB[buf][w * 512 + 4096]);        \
    gload16(gB3 + (k0), &ldsB[buf][w * 512 + 6144]);        \
  } while (0)

  STAGE1(0, 0);
  __syncthreads();
  int buf = 0;
  const int ko = (lane >> 4) * 8;
  for (int kt = 0; kt < NT; ++kt) {
    if (kt + 1 < NT) STAGE1(buf ^ 1, (kt + 1) * BK);
    bf16x8 a[8], b[4];
#pragma unroll
    for (int mf = 0; mf < 8; ++mf)
      a[mf] = *(const bf16x8*)&ldsA[buf][(mf * 16 + (lane & 15)) * BK + ko];
#pragma unroll
    for (int nf = 0; nf < 4; ++nf)
      b[nf] = *(const bf16x8*)&ldsB[buf][(w * 64 + nf * 16 + (lane & 15)) * BK + ko];
#pragma unroll
    for (int mf = 0; mf < 8; ++mf)
#pragma unroll
      for (int nf = 0; nf < 4; ++nf)
        acc[mf][nf] = __builtin_amdgcn_mfma_f32_16x16x32_bf16(a[mf], b[nf], acc[mf][nf], 0, 0, 0);
    __syncthreads();
    buf ^= 1;
  }

  const float* bin = b_in + (size_t)e * 2 * FF_DIM;
#pragma unroll
  for (int mf = 0; mf < 8; ++mf) {
    int rbase = mf * 16 + (lane >> 4) * 4;
#pragma unroll
    for (int p = 0; p < 2; ++p) {
      int f = n0f + (w * 2 + p) * 16 + (lane & 15);
      float bu = bin[f], bg = bin[FF_DIM + f];
#pragma unroll
      for (int i = 0; i < 4; ++i) {
        int mrow = mt * 128 + rbase + i;
        if (mrow < cnt) {
          float up = acc[mf][2 * p][i] + bu;
          float gt = acc[mf][2 * p + 1][i] + bg;
          up = fminf(fmaxf(up, -CLIPV), CLIPV);
          gt = fminf(fmaxf(gt, -CLIPV), CLIPV);
          float av = (gt / (1.f + expf(-gt))) * up;
          act[(size_t)(base + mrow) * FF_DIM + f] = f2bf(av);
        }
      }
    }
  }
}

// ---------------- GEMM2: BM=128 x BN=256, K-split 2, 4 waves, acc[8][4] ----------------
// grid: 2048 blocks 1-D (16e x 16mt x 4nt x 2ks), T1 swizzle.
__global__ __launch_bounds__(256, 2) void gemm2_kernel(
    const unsigned short* __restrict__ act, const unsigned short* __restrict__ woutT,
    const float* __restrict__ b_out, const int* __restrict__ offsets,
    const int* __restrict__ tok_list, const float* __restrict__ w_list,
    float* __restrict__ out) {
  __shared__ unsigned short ldsA[2][128 * BK];
  __shared__ unsigned short ldsB[2][256 * BK];
  const int lin = blockIdx.x;
  const int nid = (lin & 7) * 256 + (lin >> 3);
  const int e = nid >> 7;
  const int rem = nid & 127;
  const int mt = rem >> 3;               // [0,16)
  const int nt = (rem >> 1) & 3;         // [0,4)
  const int ks = rem & 1;                // K half: [ks*512, ks*512+512)
  const int base = offsets[e];
  const int cnt = offsets[e + 1] - base;
  if (mt * 128 >= cnt) return;
  const int n0 = nt * 256;
  const int tid = threadIdx.x, w = tid >> 6, lane = tid & 63;

  const int arow = w * 16 + (lane >> 2);
  const int m0_ = imin(mt * 128 + arow, cnt - 1);
  const int m1_ = imin(mt * 128 + arow + 64, cnt - 1);
  const int kbase = ks * 512 + (lane & 3) * 8;
  const unsigned short* gA0 = act + (size_t)(base + m0_) * FF_DIM + kbase;
  const unsigned short* gA1 = act + (size_t)(base + m1_) * FF_DIM + kbase;
  const unsigned short* we = woutT + (size_t)e * H_DIM * FF_DIM;
  const unsigned short* gB0 = we + (size_t)(n0 + arow)       * FF_DIM + kbase;
  const unsigned short* gB1 = we + (size_t)(n0 + arow + 64)  * FF_DIM + kbase;
  const unsigned short* gB2 = we + (size_t)(n0 + arow + 128) * FF_DIM + kbase;
  const unsigned short* gB3 = we + (size_t)(n0 + arow + 192) * FF_DIM + kbase;

  f32x4 acc[8][4];
#pragma unroll
  for (int m = 0; m < 8; ++m)
#pragma unroll
    for (int n = 0; n < 4; ++n) acc[m][n] = (f32x4){0.f, 0.f, 0.f, 0.f};

#define STAGE2(buf, k0)                                     \
  do {                                                      \
    gload16(gA0 + (k0), &ldsA[buf][w * 512]);               \
    gload16(gA1 + (k0), &ldsA[buf][w * 512 + 2048]);        \
    gload16(gB0 + (k0), &ldsB[buf][w * 512]);               \
    gload16(gB1 + (k0), &ldsB[buf][w * 512 + 2048]);        \
    gload16(gB2 + (k0), &ldsB[buf][w * 512 + 4096]);        \
    gload16(gB3 + (k0), &ldsB[buf][w * 512 + 6144]);        \
  } while (0)

  STAGE2(0, 0);
  __syncthreads();
  int buf = 0;
  const int ko = (lane >> 4) * 8;
  for (int kt = 0; kt < 16; ++kt) {
    if (kt + 1 < 16) STAGE2(buf ^ 1, (kt + 1) * BK);
    bf16x8 a[8], b[4];
#pragma unroll
    for (int mf = 0; mf < 8; ++mf)
      a[mf] = *(const bf16x8*)&ldsA[buf][(mf * 16 + (lane & 15)) * BK + ko];
#pragma unroll
    for (int nf = 0; nf < 4; ++nf)
      b[nf] = *(const bf16x8*)&ldsB[buf][(w * 64 + nf * 16 + (lane & 15)) * BK + ko];
#pragma unroll
    for (int mf = 0; mf < 8; ++mf)
#pragma unroll
      for (int nf = 0; nf < 4; ++nf)
        acc[mf][nf] = __builtin_amdgcn_mfma_f32_16x16x32_bf16(a[mf], b[nf], acc[mf][nf], 0, 0, 0);
    __syncthreads();
    buf ^= 1;
  }

  const float* bo = b_out + (size_t)e * H_DIM;
#pragma unroll
  for (int mf = 0; mf < 8; ++mf) {
#pragma unroll
    for (int i = 0; i < 4; ++i) {
      int mrow = mt * 128 + mf * 16 + (lane >> 4) * 4 + i;
      if (mrow < cnt) {
        int slot = base + mrow;
        int t = tok_list[slot];
        float wt = w_list[slot];
#pragma unroll
        for (int nf = 0; nf < 4; ++nf) {
          int h = n0 + w * 64 + nf * 16 + (lane & 15);
          float v = acc[mf][nf][i] + (ks == 0 ? bo[h] : 0.f);
          atomicAdd(&out[(size_t)t * H_DIM + h], wt * v);
        }
      }
    }
  }
}

// ---------------- aux loss finalize ----------------
__global__ void finalize_kernel(const float* __restrict__ imp, const int* __restrict__ pos_cnt,
                                float* __restrict__ out_aux) {
  if (threadIdx.x == 0) {
    float s = 0.f;
    for (int p = 0; p < TOPK; ++p)
      s += (imp[p] / (float)S_TOK) * ((float)pos_cnt[p] / (float)S_TOK);
    *out_aux = AUXC * (float)E_NUM * s;
  }
}

extern "C" void kernel_launch(void* const* d_in, const int* in_sizes, int n_in,
                              void* d_out, int out_size, void* d_ws, size_t ws_size,
                              hipStream_t stream) {
  const float* x     = (const float*)d_in[0];
  const float* W_in  = (const float*)d_in[1];
  const float* b_in  = (const float*)d_in[2];
  const float* W_out = (const float*)d_in[3];
  const float* b_out = (const float*)d_in[4];
  const float* rw    = (const float*)d_in[5];
  const float* rb    = (const float*)d_in[6];
  float* out = (float*)d_out;

  char* ws = (char*)d_ws;
  size_t off = 0;
  auto alloc = [&](size_t bytes) {
    void* p = ws + off;
    off = (off + bytes + 255) & ~(size_t)255;
    return p;
  };
  unsigned short* xb    = (unsigned short*)alloc((size_t)S_TOK * H_DIM * 2);
  unsigned short* winT  = (unsigned short*)alloc((size_t)E_NUM * 2 * FF_DIM * H_DIM * 2);
  unsigned short* woutT = (unsigned short*)alloc((size_t)E_NUM * H_DIM * FF_DIM * 2);
  unsigned short* act   = (unsigned short*)alloc((size_t)S_TOK * TOPK * FF_DIM * 2);
  float* logits  = (float*)alloc((size_t)S_TOK * E_NUM * 4);
  int*   topk_i  = (int*)alloc(S_TOK * TOPK * 4);
  float* topk_w  = (float*)alloc(S_TOK * TOPK * 4);
  int*   tok_list= (int*)alloc(S_TOK * TOPK * 4);
  float* w_list  = (float*)alloc(S_TOK * TOPK * 4);
  int* ctrl = (int*)alloc(64 * 4);
  int* counts = ctrl;
  int* cursor = ctrl + 16;
  int* pos_cnt = ctrl + 32;
  float* imp = (float*)(ctrl + 48);
  int* offsets = (int*)alloc(32 * 4);

  hipMemsetAsync(d_out, 0, (size_t)out_size * sizeof(float), stream);
  hipMemsetAsync(ctrl, 0, 64 * 4, stream);

  logits_kernel<<<S_TOK / 4, 256, 0, stream>>>(x, rw, rb, logits, xb);
  transpose_kernel<<<dim3(2 * FF_DIM / 64, H_DIM / 64, E_NUM), 256, 0, stream>>>(W_in, winT, H_DIM, 2 * FF_DIM);
  transpose_kernel<<<dim3(H_DIM / 64, FF_DIM / 64, E_NUM), 256, 0, stream>>>(W_out, woutT, FF_DIM, H_DIM);
  topk_kernel<<<S_TOK / 256, 256, 0, stream>>>(logits, topk_i, topk_w, counts, imp, pos_cnt);
  scan_kernel<<<1, 64, 0, stream>>>(counts, offsets);
  assign_kernel<<<S_TOK / 256, 256, 0, stream>>>(topk_i, topk_w, offsets, cursor, tok_list, w_list);
  gemm1_kernel<<<2048, 256, 0, stream>>>(xb, winT, b_in, offsets, tok_list, act);
  gemm2_kernel<<<2048, 256, 0, stream>>>(act, woutT, b_out, offsets, tok_list, w_list, out);
  finalize_kernel<<<1, 64, 0, stream>>>(imp, pos_cnt, out + (size_t)S_TOK * H_DIM);
}

// Round 6
// 224.295 us; speedup vs baseline: 1.2765x; 1.2765x over previous
//
#include <hip/hip_runtime.h>
#include <math.h>

#define S_TOK 2048
#define H_DIM 1024
#define E_NUM 16
#define FF_DIM 1024
#define TOPK 4
#define CLIPV 7.0f
#define AUXC 0.02f
#define BK 32
#define NT (H_DIM / BK)

typedef short bf16x8 __attribute__((ext_vector_type(8)));
typedef float f32x4 __attribute__((ext_vector_type(4)));

__device__ __forceinline__ unsigned short f2bf(float f) {
  unsigned int u = __float_as_uint(f);
  u += 0x7fffu + ((u >> 16) & 1u);
  return (unsigned short)(u >> 16);
}

__device__ __forceinline__ void gload16(const void* g, void* l) {
  __builtin_amdgcn_global_load_lds((const __attribute__((address_space(1))) void*)g,
                                   (__attribute__((address_space(3))) void*)l, 16, 0, 0);
}

__device__ __forceinline__ int imin(int a, int b) { return a < b ? a : b; }

// ---------------- router logits + x->bf16 convert: one wave per token ----------------
__global__ void logits_kernel(const float* __restrict__ x, const float* __restrict__ rw,
                              const float* __restrict__ rb, float* __restrict__ logits,
                              unsigned short* __restrict__ xb) {
  int tok = blockIdx.x * 4 + (threadIdx.x >> 6);
  int lane = threadIdx.x & 63;
  const float4* xr = (const float4*)(x + (size_t)tok * H_DIM);
  ushort4* xbw = (ushort4*)(xb + (size_t)tok * H_DIM);
  float p[E_NUM];
#pragma unroll
  for (int e = 0; e < E_NUM; ++e) p[e] = 0.f;
#pragma unroll
  for (int it = 0; it < 4; ++it) {
    float4 xv = xr[it * 64 + lane];
    ushort4 o;
    o.x = f2bf(xv.x); o.y = f2bf(xv.y); o.z = f2bf(xv.z); o.w = f2bf(xv.w);
    xbw[it * 64 + lane] = o;
#pragma unroll
    for (int e = 0; e < E_NUM; ++e) {
      float4 wv = ((const float4*)(rw + (size_t)e * H_DIM))[it * 64 + lane];
      p[e] += xv.x * wv.x + xv.y * wv.y + xv.z * wv.z + xv.w * wv.w;
    }
  }
#pragma unroll
  for (int e = 0; e < E_NUM; ++e) {
#pragma unroll
    for (int off = 32; off > 0; off >>= 1) p[e] += __shfl_xor(p[e], off);
  }
  if (lane == 0) {
    float4* lp = (float4*)&logits[tok * E_NUM];
#pragma unroll
    for (int q = 0; q < 4; ++q)
      lp[q] = make_float4(p[q * 4 + 0] + rb[q * 4 + 0], p[q * 4 + 1] + rb[q * 4 + 1],
                          p[q * 4 + 2] + rb[q * 4 + 2], p[q * 4 + 3] + rb[q * 4 + 3]);
  }
}

// ---------------- top-k + aux stats ----------------
__global__ __launch_bounds__(256) void topk_kernel(const float* __restrict__ logits,
                                                   int* __restrict__ topk_i, float* __restrict__ topk_w,
                                                   int* __restrict__ counts, float* __restrict__ imp,
                                                   int* __restrict__ pos_cnt) {
  __shared__ float s_imp[E_NUM];
  __shared__ int s_cnt[E_NUM];
  __shared__ int s_pos[TOPK];
  int tid = threadIdx.x;
  if (tid < E_NUM) { s_imp[tid] = 0.f; s_cnt[tid] = 0; }
  if (tid < TOPK) s_pos[tid] = 0;
  __syncthreads();

  int t = blockIdx.x * 256 + tid;
  float lg[E_NUM];
  {
    const float4* lp = (const float4*)&logits[t * E_NUM];
#pragma unroll
    for (int q = 0; q < 4; ++q) {
      float4 v = lp[q];
      lg[q * 4 + 0] = v.x; lg[q * 4 + 1] = v.y; lg[q * 4 + 2] = v.z; lg[q * 4 + 3] = v.w;
    }
  }
  int idx[TOPK]; float val[TOPK];
  float tmp[E_NUM];
#pragma unroll
  for (int e = 0; e < E_NUM; ++e) tmp[e] = lg[e];
#pragma unroll
  for (int k = 0; k < TOPK; ++k) {
    float best = -INFINITY; int bi = 0;
#pragma unroll
    for (int e = 0; e < E_NUM; ++e) if (tmp[e] > best) { best = tmp[e]; bi = e; }
    val[k] = best; idx[k] = bi; tmp[bi] = -INFINITY;
  }
  float ssum = 0.f, wv[TOPK];
#pragma unroll
  for (int k = 0; k < TOPK; ++k) { wv[k] = expf(val[k] - val[0]); ssum += wv[k]; }
#pragma unroll
  for (int k = 0; k < TOPK; ++k) wv[k] /= ssum;
#pragma unroll
  for (int k = 0; k < TOPK; ++k) {
    topk_i[t * TOPK + k] = idx[k];
    topk_w[t * TOPK + k] = wv[k];
  }
  float se = 0.f, pr[E_NUM];
#pragma unroll
  for (int e = 0; e < E_NUM; ++e) { pr[e] = expf(lg[e] - val[0]); se += pr[e]; }
  float inv = 1.f / se;
  int mi = idx[0], pos = 0;
#pragma unroll
  for (int k = 1; k < TOPK; ++k) if (idx[k] > mi) { mi = idx[k]; pos = k; }

  int lane = tid & 63;
#pragma unroll
  for (int e = 0; e < E_NUM; ++e) {
    float v = pr[e] * inv;
    int c = (idx[0] == e) + (idx[1] == e) + (idx[2] == e) + (idx[3] == e);
#pragma unroll
    for (int off = 32; off > 0; off >>= 1) {
      v += __shfl_xor(v, off);
      c += __shfl_xor(c, off);
    }
    if (lane == 0) {
      atomicAdd(&s_imp[e], v);
      atomicAdd(&s_cnt[e], c);
    }
  }
#pragma unroll
  for (int k = 0; k < TOPK; ++k) {
    int pc = (pos == k) ? 1 : 0;
#pragma unroll
    for (int off = 32; off > 0; off >>= 1) pc += __shfl_xor(pc, off);
    if (lane == 0) atomicAdd(&s_pos[k], pc);
  }
  __syncthreads();
  if (tid < E_NUM) {
    atomicAdd(&imp[tid], s_imp[tid]);
    atomicAdd(&counts[tid], s_cnt[tid]);
  }
  if (tid < TOPK) atomicAdd(&pos_cnt[tid], s_pos[tid]);
}

// ---------------- exclusive scan over 16 expert counts ----------------
__global__ void scan_kernel(const int* __restrict__ counts, int* __restrict__ offsets) {
  if (threadIdx.x == 0) {
    int off = 0;
    for (int e = 0; e < E_NUM; ++e) { offsets[e] = off; off += counts[e]; }
    offsets[E_NUM] = off;
  }
}

// ---------------- build grouped token lists + inverse slot map ----------------
__global__ __launch_bounds__(256) void assign_kernel(
    const int* __restrict__ topk_i, const int* __restrict__ offsets, int* __restrict__ cursor,
    int* __restrict__ tok_list, int* __restrict__ slot_of) {
  __shared__ int s_cnt[E_NUM];
  __shared__ int s_base[E_NUM];
  int tid = threadIdx.x;
  if (tid < E_NUM) s_cnt[tid] = 0;
  __syncthreads();
  int t = blockIdx.x * 256 + tid;
  int e[TOPK], lslot[TOPK];
#pragma unroll
  for (int k = 0; k < TOPK; ++k) {
    e[k] = topk_i[t * TOPK + k];
    lslot[k] = atomicAdd(&s_cnt[e[k]], 1);
  }
  __syncthreads();
  if (tid < E_NUM) s_base[tid] = atomicAdd(&cursor[tid], s_cnt[tid]);
  __syncthreads();
#pragma unroll
  for (int k = 0; k < TOPK; ++k) {
    int slot = offsets[e[k]] + s_base[e[k]] + lslot[k];
    tok_list[slot] = t;
    slot_of[t * TOPK + k] = slot;
  }
}

// ---------------- tiled transpose fp32 [R][C] -> bf16 [C][R], per expert slab ----------------
__global__ void transpose_kernel(const float* __restrict__ in, unsigned short* __restrict__ out,
                                 int R, int C) {
  __shared__ float tile[64][65];
  int e = blockIdx.z;
  in  += (size_t)e * R * C;
  out += (size_t)e * R * C;
  int r0 = blockIdx.y * 64, c0 = blockIdx.x * 64;
  int tx = threadIdx.x & 15, ty = threadIdx.x >> 4;
#pragma unroll
  for (int j = 0; j < 4; ++j) {
    int r = ty + j * 16;
    float4 v = *(const float4*)&in[(size_t)(r0 + r) * C + c0 + tx * 4];
    tile[r][tx * 4 + 0] = v.x; tile[r][tx * 4 + 1] = v.y;
    tile[r][tx * 4 + 2] = v.z; tile[r][tx * 4 + 3] = v.w;
  }
  __syncthreads();
#pragma unroll
  for (int j = 0; j < 4; ++j) {
    int c = ty + j * 16;
    ushort4 o;
    o.x = f2bf(tile[tx * 4 + 0][c]);
    o.y = f2bf(tile[tx * 4 + 1][c]);
    o.z = f2bf(tile[tx * 4 + 2][c]);
    o.w = f2bf(tile[tx * 4 + 3][c]);
    *(ushort4*)&out[(size_t)(c0 + c) * R + r0 + tx * 4] = o;
  }
}

// ---------------- GEMM1: BM=128 x BN=256(panel=128 f up/gate), 4 waves, acc[8][4] ----------------
// grid: 2048 blocks 1-D, T1 XCD swizzle (2048%8==0).
__global__ __launch_bounds__(256, 2) void gemm1_kernel(
    const unsigned short* __restrict__ xb, const unsigned short* __restrict__ winT,
    const float* __restrict__ b_in, const int* __restrict__ offsets,
    const int* __restrict__ tok_list, unsigned short* __restrict__ act) {
  __shared__ unsigned short ldsA[2][128 * BK];
  __shared__ unsigned short ldsB[2][256 * BK];
  const int lin = blockIdx.x;
  const int nid = (lin & 7) * 256 + (lin >> 3);   // XCD-contiguous chunks
  const int e  = nid >> 7;
  const int mt = (nid & 127) >> 3;
  const int nt = nid & 7;
  const int base = offsets[e];
  const int cnt = offsets[e + 1] - base;
  if (mt * 128 >= cnt) return;
  const int n0f = nt * 128;
  const int tid = threadIdx.x, w = tid >> 6, lane = tid & 63;

  const int arow = w * 16 + (lane >> 2);
  const int t0 = tok_list[base + imin(mt * 128 + arow, cnt - 1)];
  const int t1 = tok_list[base + imin(mt * 128 + arow + 64, cnt - 1)];
  const unsigned short* gA0 = xb + (size_t)t0 * H_DIM + (lane & 3) * 8;
  const unsigned short* gA1 = xb + (size_t)t1 * H_DIM + (lane & 3) * 8;
  auto brow_f = [&](int r) {
    int f = n0f + ((r >> 5) << 4) + (r & 15);
    return ((r >> 4) & 1) ? (FF_DIM + f) : f;
  };
  const unsigned short* we = winT + (size_t)e * 2 * FF_DIM * H_DIM;
  const unsigned short* gB0 = we + (size_t)brow_f(arow)       * H_DIM + (lane & 3) * 8;
  const unsigned short* gB1 = we + (size_t)brow_f(arow + 64)  * H_DIM + (lane & 3) * 8;
  const unsigned short* gB2 = we + (size_t)brow_f(arow + 128) * H_DIM + (lane & 3) * 8;
  const unsigned short* gB3 = we + (size_t)brow_f(arow + 192) * H_DIM + (lane & 3) * 8;

  f32x4 acc[8][4];
#pragma unroll
  for (int m = 0; m < 8; ++m)
#pragma unroll
    for (int n = 0; n < 4; ++n) acc[m][n] = (f32x4){0.f, 0.f, 0.f, 0.f};

#define STAGE1(buf, k0)                                     \
  do {                                                      \
    gload16(gA0 + (k0), &ldsA[buf][w * 512]);               \
    gload16(gA1 + (k0), &ldsA[buf][w * 512 + 2048]);        \
    gload16(gB0 + (k0), &ldsB[buf][w * 512]);               \
    gload16(gB1 + (k0), &ldsB[buf][w * 512 + 2048]);        \
    gload16(gB2 + (k0), &ldsB[buf][w * 512 + 4096]);        \
    gload16(gB3 + (k0), &ldsB[buf][w * 512 + 6144]);        \
  } while (0)

  STAGE1(0, 0);
  __syncthreads();
  int buf = 0;
  const int ko = (lane >> 4) * 8;
  for (int kt = 0; kt < NT; ++kt) {
    if (kt + 1 < NT) STAGE1(buf ^ 1, (kt + 1) * BK);
    bf16x8 a[8], b[4];
#pragma unroll
    for (int mf = 0; mf < 8; ++mf)
      a[mf] = *(const bf16x8*)&ldsA[buf][(mf * 16 + (lane & 15)) * BK + ko];
#pragma unroll
    for (int nf = 0; nf < 4; ++nf)
      b[nf] = *(const bf16x8*)&ldsB[buf][(w * 64 + nf * 16 + (lane & 15)) * BK + ko];
#pragma unroll
    for (int mf = 0; mf < 8; ++mf)
#pragma unroll
      for (int nf = 0; nf < 4; ++nf)
        acc[mf][nf] = __builtin_amdgcn_mfma_f32_16x16x32_bf16(a[mf], b[nf], acc[mf][nf], 0, 0, 0);
    __syncthreads();
    buf ^= 1;
  }

  const float* bin = b_in + (size_t)e * 2 * FF_DIM;
#pragma unroll
  for (int mf = 0; mf < 8; ++mf) {
    int rbase = mf * 16 + (lane >> 4) * 4;
#pragma unroll
    for (int p = 0; p < 2; ++p) {
      int f = n0f + (w * 2 + p) * 16 + (lane & 15);
      float bu = bin[f], bg = bin[FF_DIM + f];
#pragma unroll
      for (int i = 0; i < 4; ++i) {
        int mrow = mt * 128 + rbase + i;
        if (mrow < cnt) {
          float up = acc[mf][2 * p][i] + bu;
          float gt = acc[mf][2 * p + 1][i] + bg;
          up = fminf(fmaxf(up, -CLIPV), CLIPV);
          gt = fminf(fmaxf(gt, -CLIPV), CLIPV);
          float av = (gt / (1.f + expf(-gt))) * up;
          act[(size_t)(base + mrow) * FF_DIM + f] = f2bf(av);
        }
      }
    }
  }
}

// ---------------- GEMM2: eo[slot] = act[slot]@W_out^T + b_out (plain stores, no atomics) ----
// grid: 1024 blocks 1-D (16e x 16mt x 4nt), T1 swizzle. BM=128 x BN=256, K=1024, acc[8][4].
__global__ __launch_bounds__(256, 2) void gemm2_kernel(
    const unsigned short* __restrict__ act, const unsigned short* __restrict__ woutT,
    const float* __restrict__ b_out, const int* __restrict__ offsets,
    float* __restrict__ eo) {
  __shared__ unsigned short ldsA[2][128 * BK];
  __shared__ unsigned short ldsB[2][256 * BK];
  const int lin = blockIdx.x;
  const int nid = (lin & 7) * 128 + (lin >> 3);
  const int e = nid >> 6;
  const int rem = nid & 63;
  const int mt = rem >> 2;               // [0,16)
  const int nt = rem & 3;                // [0,4)
  const int base = offsets[e];
  const int cnt = offsets[e + 1] - base;
  if (mt * 128 >= cnt) return;
  const int n0 = nt * 256;
  const int tid = threadIdx.x, w = tid >> 6, lane = tid & 63;

  const int arow = w * 16 + (lane >> 2);
  const int m0_ = imin(mt * 128 + arow, cnt - 1);
  const int m1_ = imin(mt * 128 + arow + 64, cnt - 1);
  const int kbase = (lane & 3) * 8;
  const unsigned short* gA0 = act + (size_t)(base + m0_) * FF_DIM + kbase;
  const unsigned short* gA1 = act + (size_t)(base + m1_) * FF_DIM + kbase;
  const unsigned short* we = woutT + (size_t)e * H_DIM * FF_DIM;
  const unsigned short* gB0 = we + (size_t)(n0 + arow)       * FF_DIM + kbase;
  const unsigned short* gB1 = we + (size_t)(n0 + arow + 64)  * FF_DIM + kbase;
  const unsigned short* gB2 = we + (size_t)(n0 + arow + 128) * FF_DIM + kbase;
  const unsigned short* gB3 = we + (size_t)(n0 + arow + 192) * FF_DIM + kbase;

  f32x4 acc[8][4];
#pragma unroll
  for (int m = 0; m < 8; ++m)
#pragma unroll
    for (int n = 0; n < 4; ++n) acc[m][n] = (f32x4){0.f, 0.f, 0.f, 0.f};

#define STAGE2(buf, k0)                                     \
  do {                                                      \
    gload16(gA0 + (k0), &ldsA[buf][w * 512]);               \
    gload16(gA1 + (k0), &ldsA[buf][w * 512 + 2048]);        \
    gload16(gB0 + (k0), &ldsB[buf][w * 512]);               \
    gload16(gB1 + (k0), &ldsB[buf][w * 512 + 2048]);        \
    gload16(gB2 + (k0), &ldsB[buf][w * 512 + 4096]);        \
    gload16(gB3 + (k0), &ldsB[buf][w * 512 + 6144]);        \
  } while (0)

  STAGE2(0, 0);
  __syncthreads();
  int buf = 0;
  const int ko = (lane >> 4) * 8;
  for (int kt = 0; kt < FF_DIM / BK; ++kt) {
    if (kt + 1 < FF_DIM / BK) STAGE2(buf ^ 1, (kt + 1) * BK);
    bf16x8 a[8], b[4];
#pragma unroll
    for (int mf = 0; mf < 8; ++mf)
      a[mf] = *(const bf16x8*)&ldsA[buf][(mf * 16 + (lane & 15)) * BK + ko];
#pragma unroll
    for (int nf = 0; nf < 4; ++nf)
      b[nf] = *(const bf16x8*)&ldsB[buf][(w * 64 + nf * 16 + (lane & 15)) * BK + ko];
#pragma unroll
    for (int mf = 0; mf < 8; ++mf)
#pragma unroll
      for (int nf = 0; nf < 4; ++nf)
        acc[mf][nf] = __builtin_amdgcn_mfma_f32_16x16x32_bf16(a[mf], b[nf], acc[mf][nf], 0, 0, 0);
    __syncthreads();
    buf ^= 1;
  }

  const float* bo = b_out + (size_t)e * H_DIM;
#pragma unroll
  for (int mf = 0; mf < 8; ++mf) {
#pragma unroll
    for (int i = 0; i < 4; ++i) {
      int mrow = mt * 128 + mf * 16 + (lane >> 4) * 4 + i;
      if (mrow < cnt) {
        float* row = eo + (size_t)(base + mrow) * H_DIM;
#pragma unroll
        for (int nf = 0; nf < 4; ++nf) {
          int h = n0 + w * 64 + nf * 16 + (lane & 15);
          row[h] = acc[mf][nf][i] + bo[h];
        }
      }
    }
  }
}

// ---------------- combine: out[t] = sum_k topk_w[t][k] * eo[slot_of[t][k]] ----------------
// one block per token, 256 threads x float4 = 1024 floats
__global__ __launch_bounds__(256) void combine_kernel(
    const float* __restrict__ eo, const float* __restrict__ topk_w,
    const int* __restrict__ slot_of, float* __restrict__ out) {
  int t = blockIdx.x;
  int tid = threadIdx.x;
  float4 r = make_float4(0.f, 0.f, 0.f, 0.f);
#pragma unroll
  for (int k = 0; k < TOPK; ++k) {
    int s = slot_of[t * TOPK + k];
    float wv = topk_w[t * TOPK + k];
    float4 v = ((const float4*)(eo + (size_t)s * H_DIM))[tid];
    r.x = fmaf(wv, v.x, r.x);
    r.y = fmaf(wv, v.y, r.y);
    r.z = fmaf(wv, v.z, r.z);
    r.w = fmaf(wv, v.w, r.w);
  }
  ((float4*)(out + (size_t)t * H_DIM))[tid] = r;
}

// ---------------- aux loss finalize ----------------
__global__ void finalize_kernel(const float* __restrict__ imp, const int* __restrict__ pos_cnt,
                                float* __restrict__ out_aux) {
  if (threadIdx.x == 0) {
    float s = 0.f;
    for (int p = 0; p < TOPK; ++p)
      s += (imp[p] / (float)S_TOK) * ((float)pos_cnt[p] / (float)S_TOK);
    *out_aux = AUXC * (float)E_NUM * s;
  }
}

extern "C" void kernel_launch(void* const* d_in, const int* in_sizes, int n_in,
                              void* d_out, int out_size, void* d_ws, size_t ws_size,
                              hipStream_t stream) {
  const float* x     = (const float*)d_in[0];
  const float* W_in  = (const float*)d_in[1];
  const float* b_in  = (const float*)d_in[2];
  const float* W_out = (const float*)d_in[3];
  const float* b_out = (const float*)d_in[4];
  const float* rw    = (const float*)d_in[5];
  const float* rb    = (const float*)d_in[6];
  float* out = (float*)d_out;

  char* ws = (char*)d_ws;
  size_t off = 0;
  auto alloc = [&](size_t bytes) {
    void* p = ws + off;
    off = (off + bytes + 255) & ~(size_t)255;
    return p;
  };
  unsigned short* xb    = (unsigned short*)alloc((size_t)S_TOK * H_DIM * 2);
  unsigned short* winT  = (unsigned short*)alloc((size_t)E_NUM * 2 * FF_DIM * H_DIM * 2);
  unsigned short* woutT = (unsigned short*)alloc((size_t)E_NUM * H_DIM * FF_DIM * 2);
  unsigned short* act   = (unsigned short*)alloc((size_t)S_TOK * TOPK * FF_DIM * 2);
  float* eo      = (float*)alloc((size_t)S_TOK * TOPK * H_DIM * 4);
  float* logits  = (float*)alloc((size_t)S_TOK * E_NUM * 4);
  int*   topk_i  = (int*)alloc(S_TOK * TOPK * 4);
  float* topk_w  = (float*)alloc(S_TOK * TOPK * 4);
  int*   tok_list= (int*)alloc(S_TOK * TOPK * 4);
  int*   slot_of = (int*)alloc(S_TOK * TOPK * 4);
  int* ctrl = (int*)alloc(64 * 4);
  int* counts = ctrl;
  int* cursor = ctrl + 16;
  int* pos_cnt = ctrl + 32;
  float* imp = (float*)(ctrl + 48);
  int* offsets = (int*)alloc(32 * 4);

  hipMemsetAsync(ctrl, 0, 64 * 4, stream);

  logits_kernel<<<S_TOK / 4, 256, 0, stream>>>(x, rw, rb, logits, xb);
  transpose_kernel<<<dim3(2 * FF_DIM / 64, H_DIM / 64, E_NUM), 256, 0, stream>>>(W_in, winT, H_DIM, 2 * FF_DIM);
  transpose_kernel<<<dim3(H_DIM / 64, FF_DIM / 64, E_NUM), 256, 0, stream>>>(W_out, woutT, FF_DIM, H_DIM);
  topk_kernel<<<S_TOK / 256, 256, 0, stream>>>(logits, topk_i, topk_w, counts, imp, pos_cnt);
  scan_kernel<<<1, 64, 0, stream>>>(counts, offsets);
  assign_kernel<<<S_TOK / 256, 256, 0, stream>>>(topk_i, offsets, cursor, tok_list, slot_of);
  gemm1_kernel<<<2048, 256, 0, stream>>>(xb, winT, b_in, offsets, tok_list, act);
  gemm2_kernel<<<1024, 256, 0, stream>>>(act, woutT, b_out, offsets, eo);
  combine_kernel<<<S_TOK, 256, 0, stream>>>(eo, topk_w, slot_of, out);
  finalize_kernel<<<1, 64, 0, stream>>>(imp, pos_cnt, out + (size_t)S_TOK * H_DIM);
}

// Round 7
// 216.317 us; speedup vs baseline: 1.3235x; 1.0369x over previous
//
#include <hip/hip_runtime.h>
#include <math.h>

#define S_TOK 2048
#define H_DIM 1024
#define E_NUM 16
#define FF_DIM 1024
#define TOPK 4
#define CLIPV 7.0f
#define AUXC 0.02f
#define BK 32
#define NT (H_DIM / BK)

typedef short bf16x8 __attribute__((ext_vector_type(8)));
typedef float f32x4 __attribute__((ext_vector_type(4)));

__device__ __forceinline__ unsigned short f2bf(float f) {
  unsigned int u = __float_as_uint(f);
  u += 0x7fffu + ((u >> 16) & 1u);
  return (unsigned short)(u >> 16);
}

__device__ __forceinline__ void gload16(const void* g, void* l) {
  __builtin_amdgcn_global_load_lds((const __attribute__((address_space(1))) void*)g,
                                   (__attribute__((address_space(3))) void*)l, 16, 0, 0);
}

__device__ __forceinline__ int imin(int a, int b) { return a < b ? a : b; }

// ---------------- router logits + x->bf16 convert: one wave per token ----------------
__global__ void logits_kernel(const float* __restrict__ x, const float* __restrict__ rw,
                              const float* __restrict__ rb, float* __restrict__ logits,
                              unsigned short* __restrict__ xb) {
  int tok = blockIdx.x * 4 + (threadIdx.x >> 6);
  int lane = threadIdx.x & 63;
  const float4* xr = (const float4*)(x + (size_t)tok * H_DIM);
  ushort4* xbw = (ushort4*)(xb + (size_t)tok * H_DIM);
  float p[E_NUM];
#pragma unroll
  for (int e = 0; e < E_NUM; ++e) p[e] = 0.f;
#pragma unroll
  for (int it = 0; it < 4; ++it) {
    float4 xv = xr[it * 64 + lane];
    ushort4 o;
    o.x = f2bf(xv.x); o.y = f2bf(xv.y); o.z = f2bf(xv.z); o.w = f2bf(xv.w);
    xbw[it * 64 + lane] = o;
#pragma unroll
    for (int e = 0; e < E_NUM; ++e) {
      float4 wv = ((const float4*)(rw + (size_t)e * H_DIM))[it * 64 + lane];
      p[e] += xv.x * wv.x + xv.y * wv.y + xv.z * wv.z + xv.w * wv.w;
    }
  }
#pragma unroll
  for (int e = 0; e < E_NUM; ++e) {
#pragma unroll
    for (int off = 32; off > 0; off >>= 1) p[e] += __shfl_xor(p[e], off);
  }
  if (lane == 0) {
    float4* lp = (float4*)&logits[tok * E_NUM];
#pragma unroll
    for (int q = 0; q < 4; ++q)
      lp[q] = make_float4(p[q * 4 + 0] + rb[q * 4 + 0], p[q * 4 + 1] + rb[q * 4 + 1],
                          p[q * 4 + 2] + rb[q * 4 + 2], p[q * 4 + 3] + rb[q * 4 + 3]);
  }
}

// ---------------- top-k + aux stats ----------------
__global__ __launch_bounds__(256) void topk_kernel(const float* __restrict__ logits,
                                                   int* __restrict__ topk_i, float* __restrict__ topk_w,
                                                   int* __restrict__ counts, float* __restrict__ imp,
                                                   int* __restrict__ pos_cnt) {
  __shared__ float s_imp[E_NUM];
  __shared__ int s_cnt[E_NUM];
  __shared__ int s_pos[TOPK];
  int tid = threadIdx.x;
  if (tid < E_NUM) { s_imp[tid] = 0.f; s_cnt[tid] = 0; }
  if (tid < TOPK) s_pos[tid] = 0;
  __syncthreads();

  int t = blockIdx.x * 256 + tid;
  float lg[E_NUM];
  {
    const float4* lp = (const float4*)&logits[t * E_NUM];
#pragma unroll
    for (int q = 0; q < 4; ++q) {
      float4 v = lp[q];
      lg[q * 4 + 0] = v.x; lg[q * 4 + 1] = v.y; lg[q * 4 + 2] = v.z; lg[q * 4 + 3] = v.w;
    }
  }
  int idx[TOPK]; float val[TOPK];
  float tmp[E_NUM];
#pragma unroll
  for (int e = 0; e < E_NUM; ++e) tmp[e] = lg[e];
#pragma unroll
  for (int k = 0; k < TOPK; ++k) {
    float best = -INFINITY; int bi = 0;
#pragma unroll
    for (int e = 0; e < E_NUM; ++e) if (tmp[e] > best) { best = tmp[e]; bi = e; }
    val[k] = best; idx[k] = bi; tmp[bi] = -INFINITY;
  }
  float ssum = 0.f, wv[TOPK];
#pragma unroll
  for (int k = 0; k < TOPK; ++k) { wv[k] = expf(val[k] - val[0]); ssum += wv[k]; }
#pragma unroll
  for (int k = 0; k < TOPK; ++k) wv[k] /= ssum;
#pragma unroll
  for (int k = 0; k < TOPK; ++k) {
    topk_i[t * TOPK + k] = idx[k];
    topk_w[t * TOPK + k] = wv[k];
  }
  float se = 0.f, pr[E_NUM];
#pragma unroll
  for (int e = 0; e < E_NUM; ++e) { pr[e] = expf(lg[e] - val[0]); se += pr[e]; }
  float inv = 1.f / se;
  int mi = idx[0], pos = 0;
#pragma unroll
  for (int k = 1; k < TOPK; ++k) if (idx[k] > mi) { mi = idx[k]; pos = k; }

  int lane = tid & 63;
#pragma unroll
  for (int e = 0; e < E_NUM; ++e) {
    float v = pr[e] * inv;
    int c = (idx[0] == e) + (idx[1] == e) + (idx[2] == e) + (idx[3] == e);
#pragma unroll
    for (int off = 32; off > 0; off >>= 1) {
      v += __shfl_xor(v, off);
      c += __shfl_xor(c, off);
    }
    if (lane == 0) {
      atomicAdd(&s_imp[e], v);
      atomicAdd(&s_cnt[e], c);
    }
  }
#pragma unroll
  for (int k = 0; k < TOPK; ++k) {
    int pc = (pos == k) ? 1 : 0;
#pragma unroll
    for (int off = 32; off > 0; off >>= 1) pc += __shfl_xor(pc, off);
    if (lane == 0) atomicAdd(&s_pos[k], pc);
  }
  __syncthreads();
  if (tid < E_NUM) {
    atomicAdd(&imp[tid], s_imp[tid]);
    atomicAdd(&counts[tid], s_cnt[tid]);
  }
  if (tid < TOPK) atomicAdd(&pos_cnt[tid], s_pos[tid]);
}

// ---------------- exclusive scan over 16 expert counts ----------------
__global__ void scan_kernel(const int* __restrict__ counts, int* __restrict__ offsets) {
  if (threadIdx.x == 0) {
    int off = 0;
    for (int e = 0; e < E_NUM; ++e) { offsets[e] = off; off += counts[e]; }
    offsets[E_NUM] = off;
  }
}

// ---------------- build grouped token lists + inverse slot map ----------------
__global__ __launch_bounds__(256) void assign_kernel(
    const int* __restrict__ topk_i, const int* __restrict__ offsets, int* __restrict__ cursor,
    int* __restrict__ tok_list, int* __restrict__ slot_of) {
  __shared__ int s_cnt[E_NUM];
  __shared__ int s_base[E_NUM];
  int tid = threadIdx.x;
  if (tid < E_NUM) s_cnt[tid] = 0;
  __syncthreads();
  int t = blockIdx.x * 256 + tid;
  int e[TOPK], lslot[TOPK];
#pragma unroll
  for (int k = 0; k < TOPK; ++k) {
    e[k] = topk_i[t * TOPK + k];
    lslot[k] = atomicAdd(&s_cnt[e[k]], 1);
  }
  __syncthreads();
  if (tid < E_NUM) s_base[tid] = atomicAdd(&cursor[tid], s_cnt[tid]);
  __syncthreads();
#pragma unroll
  for (int k = 0; k < TOPK; ++k) {
    int slot = offsets[e[k]] + s_base[e[k]] + lslot[k];
    tok_list[slot] = t;
    slot_of[t * TOPK + k] = slot;
  }
}

// ---------------- tiled transpose fp32 [R][C] -> bf16 [C][R], per expert slab ----------------
__global__ void transpose_kernel(const float* __restrict__ in, unsigned short* __restrict__ out,
                                 int R, int C) {
  __shared__ float tile[64][65];
  int e = blockIdx.z;
  in  += (size_t)e * R * C;
  out += (size_t)e * R * C;
  int r0 = blockIdx.y * 64, c0 = blockIdx.x * 64;
  int tx = threadIdx.x & 15, ty = threadIdx.x >> 4;
#pragma unroll
  for (int j = 0; j < 4; ++j) {
    int r = ty + j * 16;
    float4 v = *(const float4*)&in[(size_t)(r0 + r) * C + c0 + tx * 4];
    tile[r][tx * 4 + 0] = v.x; tile[r][tx * 4 + 1] = v.y;
    tile[r][tx * 4 + 2] = v.z; tile[r][tx * 4 + 3] = v.w;
  }
  __syncthreads();
#pragma unroll
  for (int j = 0; j < 4; ++j) {
    int c = ty + j * 16;
    ushort4 o;
    o.x = f2bf(tile[tx * 4 + 0][c]);
    o.y = f2bf(tile[tx * 4 + 1][c]);
    o.z = f2bf(tile[tx * 4 + 2][c]);
    o.w = f2bf(tile[tx * 4 + 3][c]);
    *(ushort4*)&out[(size_t)(c0 + c) * R + r0 + tx * 4] = o;
  }
}

// ---------------- GEMM1: BM=128 x BN=256(panel), counted-vmcnt triple-buffer pipeline -----
// grid: 2048 blocks. nid = e*128 + nt*16 + mt (mt FAST within XCD -> B panel hot in L2).
__global__ __launch_bounds__(256, 2) void gemm1_kernel(
    const unsigned short* __restrict__ xb, const unsigned short* __restrict__ winT,
    const float* __restrict__ b_in, const int* __restrict__ offsets,
    const int* __restrict__ tok_list, unsigned short* __restrict__ act) {
  __shared__ unsigned short ldsA[3][128 * BK];
  __shared__ unsigned short ldsB[3][256 * BK];
  const int lin = blockIdx.x;
  const int nid = (lin & 7) * 256 + (lin >> 3);   // XCD x -> nids [x*256, x*256+256)
  const int e  = nid >> 7;
  const int nt = (nid >> 4) & 7;
  const int mt = nid & 15;
  const int base = offsets[e];
  const int cnt = offsets[e + 1] - base;
  if (mt * 128 >= cnt) return;
  const int n0f = nt * 128;
  const int tid = threadIdx.x, w = tid >> 6, lane = tid & 63;

  const int arow = w * 16 + (lane >> 2);
  const int t0 = tok_list[base + imin(mt * 128 + arow, cnt - 1)];
  const int t1 = tok_list[base + imin(mt * 128 + arow + 64, cnt - 1)];
  const unsigned short* gA0 = xb + (size_t)t0 * H_DIM + (lane & 3) * 8;
  const unsigned short* gA1 = xb + (size_t)t1 * H_DIM + (lane & 3) * 8;
  auto brow_f = [&](int r) {
    int f = n0f + ((r >> 5) << 4) + (r & 15);
    return ((r >> 4) & 1) ? (FF_DIM + f) : f;
  };
  const unsigned short* we = winT + (size_t)e * 2 * FF_DIM * H_DIM;
  const unsigned short* gB0 = we + (size_t)brow_f(arow)       * H_DIM + (lane & 3) * 8;
  const unsigned short* gB1 = we + (size_t)brow_f(arow + 64)  * H_DIM + (lane & 3) * 8;
  const unsigned short* gB2 = we + (size_t)brow_f(arow + 128) * H_DIM + (lane & 3) * 8;
  const unsigned short* gB3 = we + (size_t)brow_f(arow + 192) * H_DIM + (lane & 3) * 8;

  f32x4 acc[8][4];
#pragma unroll
  for (int m = 0; m < 8; ++m)
#pragma unroll
    for (int n = 0; n < 4; ++n) acc[m][n] = (f32x4){0.f, 0.f, 0.f, 0.f};

#define STAGE1(buf, k0)                                     \
  do {                                                      \
    gload16(gA0 + (k0), &ldsA[buf][w * 512]);               \
    gload16(gA1 + (k0), &ldsA[buf][w * 512 + 2048]);        \
    gload16(gB0 + (k0), &ldsB[buf][w * 512]);               \
    gload16(gB1 + (k0), &ldsB[buf][w * 512 + 2048]);        \
    gload16(gB2 + (k0), &ldsB[buf][w * 512 + 4096]);        \
    gload16(gB3 + (k0), &ldsB[buf][w * 512 + 6144]);        \
  } while (0)

  STAGE1(0, 0);
  STAGE1(1, BK);
  int buf = 0;
  for (int kt = 0; kt < NT; ++kt) {
    int nb = buf + 2; if (nb >= 3) nb -= 3;
    if (kt + 2 < NT) {
      STAGE1(nb, (kt + 2) * BK);
      asm volatile("s_waitcnt vmcnt(12)" ::: "memory");  // group kt done; kt+1,kt+2 in flight
    } else if (kt + 2 == NT) {
      asm volatile("s_waitcnt vmcnt(6)" ::: "memory");
    } else {
      asm volatile("s_waitcnt vmcnt(0)" ::: "memory");
    }
    __builtin_amdgcn_s_barrier();
    bf16x8 a[8], b[4];
    const int ko = (lane >> 4) * 8;
#pragma unroll
    for (int mf = 0; mf < 8; ++mf)
      a[mf] = *(const bf16x8*)&ldsA[buf][(mf * 16 + (lane & 15)) * BK + ko];
#pragma unroll
    for (int nf = 0; nf < 4; ++nf)
      b[nf] = *(const bf16x8*)&ldsB[buf][(w * 64 + nf * 16 + (lane & 15)) * BK + ko];
#pragma unroll
    for (int mf = 0; mf < 8; ++mf)
#pragma unroll
      for (int nf = 0; nf < 4; ++nf)
        acc[mf][nf] = __builtin_amdgcn_mfma_f32_16x16x32_bf16(a[mf], b[nf], acc[mf][nf], 0, 0, 0);
    __builtin_amdgcn_s_barrier();
    buf = (buf == 2) ? 0 : buf + 1;
  }

  const float* bin = b_in + (size_t)e * 2 * FF_DIM;
#pragma unroll
  for (int mf = 0; mf < 8; ++mf) {
    int rbase = mf * 16 + (lane >> 4) * 4;
#pragma unroll
    for (int p = 0; p < 2; ++p) {
      int f = n0f + (w * 2 + p) * 16 + (lane & 15);
      float bu = bin[f], bg = bin[FF_DIM + f];
#pragma unroll
      for (int i = 0; i < 4; ++i) {
        int mrow = mt * 128 + rbase + i;
        if (mrow < cnt) {
          float up = acc[mf][2 * p][i] + bu;
          float gt = acc[mf][2 * p + 1][i] + bg;
          up = fminf(fmaxf(up, -CLIPV), CLIPV);
          gt = fminf(fmaxf(gt, -CLIPV), CLIPV);
          float av = (gt / (1.f + expf(-gt))) * up;
          act[(size_t)(base + mrow) * FF_DIM + f] = f2bf(av);
        }
      }
    }
  }
}

// ---------------- GEMM2: eo[slot] = act[slot]@W_out^T + b_out, same pipeline ----------------
// grid: 1024 blocks. nid = e*64 + nt*16 + mt (mt FAST).
__global__ __launch_bounds__(256, 2) void gemm2_kernel(
    const unsigned short* __restrict__ act, const unsigned short* __restrict__ woutT,
    const float* __restrict__ b_out, const int* __restrict__ offsets,
    float* __restrict__ eo) {
  __shared__ unsigned short ldsA[3][128 * BK];
  __shared__ unsigned short ldsB[3][256 * BK];
  const int lin = blockIdx.x;
  const int nid = (lin & 7) * 128 + (lin >> 3);
  const int e = nid >> 6;
  const int nt = (nid >> 4) & 3;
  const int mt = nid & 15;
  const int base = offsets[e];
  const int cnt = offsets[e + 1] - base;
  if (mt * 128 >= cnt) return;
  const int n0 = nt * 256;
  const int tid = threadIdx.x, w = tid >> 6, lane = tid & 63;

  const int arow = w * 16 + (lane >> 2);
  const int m0_ = imin(mt * 128 + arow, cnt - 1);
  const int m1_ = imin(mt * 128 + arow + 64, cnt - 1);
  const int kbase = (lane & 3) * 8;
  const unsigned short* gA0 = act + (size_t)(base + m0_) * FF_DIM + kbase;
  const unsigned short* gA1 = act + (size_t)(base + m1_) * FF_DIM + kbase;
  const unsigned short* we = woutT + (size_t)e * H_DIM * FF_DIM;
  const unsigned short* gB0 = we + (size_t)(n0 + arow)       * FF_DIM + kbase;
  const unsigned short* gB1 = we + (size_t)(n0 + arow + 64)  * FF_DIM + kbase;
  const unsigned short* gB2 = we + (size_t)(n0 + arow + 128) * FF_DIM + kbase;
  const unsigned short* gB3 = we + (size_t)(n0 + arow + 192) * FF_DIM + kbase;

  f32x4 acc[8][4];
#pragma unroll
  for (int m = 0; m < 8; ++m)
#pragma unroll
    for (int n = 0; n < 4; ++n) acc[m][n] = (f32x4){0.f, 0.f, 0.f, 0.f};

#define STAGE2(buf, k0)                                     \
  do {                                                      \
    gload16(gA0 + (k0), &ldsA[buf][w * 512]);               \
    gload16(gA1 + (k0), &ldsA[buf][w * 512 + 2048]);        \
    gload16(gB0 + (k0), &ldsB[buf][w * 512]);               \
    gload16(gB1 + (k0), &ldsB[buf][w * 512 + 2048]);        \
    gload16(gB2 + (k0), &ldsB[buf][w * 512 + 4096]);        \
    gload16(gB3 + (k0), &ldsB[buf][w * 512 + 6144]);        \
  } while (0)

  STAGE2(0, 0);
  STAGE2(1, BK);
  int buf = 0;
  for (int kt = 0; kt < FF_DIM / BK; ++kt) {
    int nb = buf + 2; if (nb >= 3) nb -= 3;
    if (kt + 2 < FF_DIM / BK) {
      STAGE2(nb, (kt + 2) * BK);
      asm volatile("s_waitcnt vmcnt(12)" ::: "memory");
    } else if (kt + 2 == FF_DIM / BK) {
      asm volatile("s_waitcnt vmcnt(6)" ::: "memory");
    } else {
      asm volatile("s_waitcnt vmcnt(0)" ::: "memory");
    }
    __builtin_amdgcn_s_barrier();
    bf16x8 a[8], b[4];
    const int ko = (lane >> 4) * 8;
#pragma unroll
    for (int mf = 0; mf < 8; ++mf)
      a[mf] = *(const bf16x8*)&ldsA[buf][(mf * 16 + (lane & 15)) * BK + ko];
#pragma unroll
    for (int nf = 0; nf < 4; ++nf)
      b[nf] = *(const bf16x8*)&ldsB[buf][(w * 64 + nf * 16 + (lane & 15)) * BK + ko];
#pragma unroll
    for (int mf = 0; mf < 8; ++mf)
#pragma unroll
      for (int nf = 0; nf < 4; ++nf)
        acc[mf][nf] = __builtin_amdgcn_mfma_f32_16x16x32_bf16(a[mf], b[nf], acc[mf][nf], 0, 0, 0);
    __builtin_amdgcn_s_barrier();
    buf = (buf == 2) ? 0 : buf + 1;
  }

  const float* bo = b_out + (size_t)e * H_DIM;
#pragma unroll
  for (int mf = 0; mf < 8; ++mf) {
#pragma unroll
    for (int i = 0; i < 4; ++i) {
      int mrow = mt * 128 + mf * 16 + (lane >> 4) * 4 + i;
      if (mrow < cnt) {
        float* row = eo + (size_t)(base + mrow) * H_DIM;
#pragma unroll
        for (int nf = 0; nf < 4; ++nf) {
          int h = n0 + w * 64 + nf * 16 + (lane & 15);
          row[h] = acc[mf][nf][i] + bo[h];
        }
      }
    }
  }
}

// ---------------- combine: out[t] = sum_k topk_w[t][k] * eo[slot_of[t][k]] ----------------
__global__ __launch_bounds__(256) void combine_kernel(
    const float* __restrict__ eo, const float* __restrict__ topk_w,
    const int* __restrict__ slot_of, float* __restrict__ out) {
  int t = blockIdx.x;
  int tid = threadIdx.x;
  float4 r = make_float4(0.f, 0.f, 0.f, 0.f);
#pragma unroll
  for (int k = 0; k < TOPK; ++k) {
    int s = slot_of[t * TOPK + k];
    float wv = topk_w[t * TOPK + k];
    float4 v = ((const float4*)(eo + (size_t)s * H_DIM))[tid];
    r.x = fmaf(wv, v.x, r.x);
    r.y = fmaf(wv, v.y, r.y);
    r.z = fmaf(wv, v.z, r.z);
    r.w = fmaf(wv, v.w, r.w);
  }
  ((float4*)(out + (size_t)t * H_DIM))[tid] = r;
}

// ---------------- aux loss finalize ----------------
__global__ void finalize_kernel(const float* __restrict__ imp, const int* __restrict__ pos_cnt,
                                float* __restrict__ out_aux) {
  if (threadIdx.x == 0) {
    float s = 0.f;
    for (int p = 0; p < TOPK; ++p)
      s += (imp[p] / (float)S_TOK) * ((float)pos_cnt[p] / (float)S_TOK);
    *out_aux = AUXC * (float)E_NUM * s;
  }
}

extern "C" void kernel_launch(void* const* d_in, const int* in_sizes, int n_in,
                              void* d_out, int out_size, void* d_ws, size_t ws_size,
                              hipStream_t stream) {
  const float* x     = (const float*)d_in[0];
  const float* W_in  = (const float*)d_in[1];
  const float* b_in  = (const float*)d_in[2];
  const float* W_out = (const float*)d_in[3];
  const float* b_out = (const float*)d_in[4];
  const float* rw    = (const float*)d_in[5];
  const float* rb    = (const float*)d_in[6];
  float* out = (float*)d_out;

  char* ws = (char*)d_ws;
  size_t off = 0;
  auto alloc = [&](size_t bytes) {
    void* p = ws + off;
    off = (off + bytes + 255) & ~(size_t)255;
    return p;
  };
  unsigned short* xb    = (unsigned short*)alloc((size_t)S_TOK * H_DIM * 2);
  unsigned short* winT  = (unsigned short*)alloc((size_t)E_NUM * 2 * FF_DIM * H_DIM * 2);
  unsigned short* woutT = (unsigned short*)alloc((size_t)E_NUM * H_DIM * FF_DIM * 2);
  unsigned short* act   = (unsigned short*)alloc((size_t)S_TOK * TOPK * FF_DIM * 2);
  float* eo      = (float*)alloc((size_t)S_TOK * TOPK * H_DIM * 4);
  float* logits  = (float*)alloc((size_t)S_TOK * E_NUM * 4);
  int*   topk_i  = (int*)alloc(S_TOK * TOPK * 4);
  float* topk_w  = (float*)alloc(S_TOK * TOPK * 4);
  int*   tok_list= (int*)alloc(S_TOK * TOPK * 4);
  int*   slot_of = (int*)alloc(S_TOK * TOPK * 4);
  int* ctrl = (int*)alloc(64 * 4);
  int* counts = ctrl;
  int* cursor = ctrl + 16;
  int* pos_cnt = ctrl + 32;
  float* imp = (float*)(ctrl + 48);
  int* offsets = (int*)alloc(32 * 4);

  hipMemsetAsync(ctrl, 0, 64 * 4, stream);

  logits_kernel<<<S_TOK / 4, 256, 0, stream>>>(x, rw, rb, logits, xb);
  transpose_kernel<<<dim3(2 * FF_DIM / 64, H_DIM / 64, E_NUM), 256, 0, stream>>>(W_in, winT, H_DIM, 2 * FF_DIM);
  transpose_kernel<<<dim3(H_DIM / 64, FF_DIM / 64, E_NUM), 256, 0, stream>>>(W_out, woutT, FF_DIM, H_DIM);
  topk_kernel<<<S_TOK / 256, 256, 0, stream>>>(logits, topk_i, topk_w, counts, imp, pos_cnt);
  scan_kernel<<<1, 64, 0, stream>>>(counts, offsets);
  assign_kernel<<<S_TOK / 256, 256, 0, stream>>>(topk_i, offsets, cursor, tok_list, slot_of);
  gemm1_kernel<<<2048, 256, 0, stream>>>(xb, winT, b_in, offsets, tok_list, act);
  gemm2_kernel<<<1024, 256, 0, stream>>>(act, woutT, b_out, offsets, eo);
  combine_kernel<<<S_TOK, 256, 0, stream>>>(eo, topk_w, slot_of, out);
  finalize_kernel<<<1, 64, 0, stream>>>(imp, pos_cnt, out + (size_t)S_TOK * H_DIM);
}

// Round 8
// 199.267 us; speedup vs baseline: 1.4368x; 1.0856x over previous
//
#include <hip/hip_runtime.h>
#include <math.h>

#define S_TOK 2048
#define H_DIM 1024
#define E_NUM 16
#define FF_DIM 1024
#define TOPK 4
#define CLIPV 7.0f
#define AUXC 0.02f
#define BK 32
#define NT (H_DIM / BK)

typedef short bf16x8 __attribute__((ext_vector_type(8)));
typedef float f32x4 __attribute__((ext_vector_type(4)));

__device__ __forceinline__ unsigned short f2bf(float f) {
  unsigned int u = __float_as_uint(f);
  u += 0x7fffu + ((u >> 16) & 1u);
  return (unsigned short)(u >> 16);
}

__device__ __forceinline__ void gload16(const void* g, void* l) {
  __builtin_amdgcn_global_load_lds((const __attribute__((address_space(1))) void*)g,
                                   (__attribute__((address_space(3))) void*)l, 16, 0, 0);
}

__device__ __forceinline__ int imin(int a, int b) { return a < b ? a : b; }

// ---------------- router logits + x->bf16 convert: one wave per token ----------------
__global__ void logits_kernel(const float* __restrict__ x, const float* __restrict__ rw,
                              const float* __restrict__ rb, float* __restrict__ logits,
                              unsigned short* __restrict__ xb) {
  int tok = blockIdx.x * 4 + (threadIdx.x >> 6);
  int lane = threadIdx.x & 63;
  const float4* xr = (const float4*)(x + (size_t)tok * H_DIM);
  ushort4* xbw = (ushort4*)(xb + (size_t)tok * H_DIM);
  float p[E_NUM];
#pragma unroll
  for (int e = 0; e < E_NUM; ++e) p[e] = 0.f;
#pragma unroll
  for (int it = 0; it < 4; ++it) {
    float4 xv = xr[it * 64 + lane];
    ushort4 o;
    o.x = f2bf(xv.x); o.y = f2bf(xv.y); o.z = f2bf(xv.z); o.w = f2bf(xv.w);
    xbw[it * 64 + lane] = o;
#pragma unroll
    for (int e = 0; e < E_NUM; ++e) {
      float4 wv = ((const float4*)(rw + (size_t)e * H_DIM))[it * 64 + lane];
      p[e] += xv.x * wv.x + xv.y * wv.y + xv.z * wv.z + xv.w * wv.w;
    }
  }
#pragma unroll
  for (int e = 0; e < E_NUM; ++e) {
#pragma unroll
    for (int off = 32; off > 0; off >>= 1) p[e] += __shfl_xor(p[e], off);
  }
  if (lane == 0) {
    float4* lp = (float4*)&logits[tok * E_NUM];
#pragma unroll
    for (int q = 0; q < 4; ++q)
      lp[q] = make_float4(p[q * 4 + 0] + rb[q * 4 + 0], p[q * 4 + 1] + rb[q * 4 + 1],
                          p[q * 4 + 2] + rb[q * 4 + 2], p[q * 4 + 3] + rb[q * 4 + 3]);
  }
}

// ---------------- top-k + aux stats ----------------
__global__ __launch_bounds__(256) void topk_kernel(const float* __restrict__ logits,
                                                   int* __restrict__ topk_i, float* __restrict__ topk_w,
                                                   int* __restrict__ counts, float* __restrict__ imp,
                                                   int* __restrict__ pos_cnt) {
  __shared__ float s_imp[E_NUM];
  __shared__ int s_cnt[E_NUM];
  __shared__ int s_pos[TOPK];
  int tid = threadIdx.x;
  if (tid < E_NUM) { s_imp[tid] = 0.f; s_cnt[tid] = 0; }
  if (tid < TOPK) s_pos[tid] = 0;
  __syncthreads();

  int t = blockIdx.x * 256 + tid;
  float lg[E_NUM];
  {
    const float4* lp = (const float4*)&logits[t * E_NUM];
#pragma unroll
    for (int q = 0; q < 4; ++q) {
      float4 v = lp[q];
      lg[q * 4 + 0] = v.x; lg[q * 4 + 1] = v.y; lg[q * 4 + 2] = v.z; lg[q * 4 + 3] = v.w;
    }
  }
  int idx[TOPK]; float val[TOPK];
  float tmp[E_NUM];
#pragma unroll
  for (int e = 0; e < E_NUM; ++e) tmp[e] = lg[e];
#pragma unroll
  for (int k = 0; k < TOPK; ++k) {
    float best = -INFINITY; int bi = 0;
#pragma unroll
    for (int e = 0; e < E_NUM; ++e) if (tmp[e] > best) { best = tmp[e]; bi = e; }
    val[k] = best; idx[k] = bi; tmp[bi] = -INFINITY;
  }
  float ssum = 0.f, wv[TOPK];
#pragma unroll
  for (int k = 0; k < TOPK; ++k) { wv[k] = expf(val[k] - val[0]); ssum += wv[k]; }
#pragma unroll
  for (int k = 0; k < TOPK; ++k) wv[k] /= ssum;
#pragma unroll
  for (int k = 0; k < TOPK; ++k) {
    topk_i[t * TOPK + k] = idx[k];
    topk_w[t * TOPK + k] = wv[k];
  }
  float se = 0.f, pr[E_NUM];
#pragma unroll
  for (int e = 0; e < E_NUM; ++e) { pr[e] = expf(lg[e] - val[0]); se += pr[e]; }
  float inv = 1.f / se;
  int mi = idx[0], pos = 0;
#pragma unroll
  for (int k = 1; k < TOPK; ++k) if (idx[k] > mi) { mi = idx[k]; pos = k; }

  int lane = tid & 63;
#pragma unroll
  for (int e = 0; e < E_NUM; ++e) {
    float v = pr[e] * inv;
    int c = (idx[0] == e) + (idx[1] == e) + (idx[2] == e) + (idx[3] == e);
#pragma unroll
    for (int off = 32; off > 0; off >>= 1) {
      v += __shfl_xor(v, off);
      c += __shfl_xor(c, off);
    }
    if (lane == 0) {
      atomicAdd(&s_imp[e], v);
      atomicAdd(&s_cnt[e], c);
    }
  }
#pragma unroll
  for (int k = 0; k < TOPK; ++k) {
    int pc = (pos == k) ? 1 : 0;
#pragma unroll
    for (int off = 32; off > 0; off >>= 1) pc += __shfl_xor(pc, off);
    if (lane == 0) atomicAdd(&s_pos[k], pc);
  }
  __syncthreads();
  if (tid < E_NUM) {
    atomicAdd(&imp[tid], s_imp[tid]);
    atomicAdd(&counts[tid], s_cnt[tid]);
  }
  if (tid < TOPK) atomicAdd(&pos_cnt[tid], s_pos[tid]);
}

// ---------------- exclusive scan over 16 expert counts ----------------
__global__ void scan_kernel(const int* __restrict__ counts, int* __restrict__ offsets) {
  if (threadIdx.x == 0) {
    int off = 0;
    for (int e = 0; e < E_NUM; ++e) { offsets[e] = off; off += counts[e]; }
    offsets[E_NUM] = off;
  }
}

// ---------------- build grouped token lists + inverse slot map ----------------
__global__ __launch_bounds__(256) void assign_kernel(
    const int* __restrict__ topk_i, const int* __restrict__ offsets, int* __restrict__ cursor,
    int* __restrict__ tok_list, int* __restrict__ slot_of) {
  __shared__ int s_cnt[E_NUM];
  __shared__ int s_base[E_NUM];
  int tid = threadIdx.x;
  if (tid < E_NUM) s_cnt[tid] = 0;
  __syncthreads();
  int t = blockIdx.x * 256 + tid;
  int e[TOPK], lslot[TOPK];
#pragma unroll
  for (int k = 0; k < TOPK; ++k) {
    e[k] = topk_i[t * TOPK + k];
    lslot[k] = atomicAdd(&s_cnt[e[k]], 1);
  }
  __syncthreads();
  if (tid < E_NUM) s_base[tid] = atomicAdd(&cursor[tid], s_cnt[tid]);
  __syncthreads();
#pragma unroll
  for (int k = 0; k < TOPK; ++k) {
    int slot = offsets[e[k]] + s_base[e[k]] + lslot[k];
    tok_list[slot] = t;
    slot_of[t * TOPK + k] = slot;
  }
}

// ---------------- tiled transpose fp32 [R][C] -> bf16 [C][R], per expert slab ----------------
__global__ void transpose_kernel(const float* __restrict__ in, unsigned short* __restrict__ out,
                                 int R, int C) {
  __shared__ float tile[64][65];
  int e = blockIdx.z;
  in  += (size_t)e * R * C;
  out += (size_t)e * R * C;
  int r0 = blockIdx.y * 64, c0 = blockIdx.x * 64;
  int tx = threadIdx.x & 15, ty = threadIdx.x >> 4;
#pragma unroll
  for (int j = 0; j < 4; ++j) {
    int r = ty + j * 16;
    float4 v = *(const float4*)&in[(size_t)(r0 + r) * C + c0 + tx * 4];
    tile[r][tx * 4 + 0] = v.x; tile[r][tx * 4 + 1] = v.y;
    tile[r][tx * 4 + 2] = v.z; tile[r][tx * 4 + 3] = v.w;
  }
  __syncthreads();
#pragma unroll
  for (int j = 0; j < 4; ++j) {
    int c = ty + j * 16;
    ushort4 o;
    o.x = f2bf(tile[tx * 4 + 0][c]);
    o.y = f2bf(tile[tx * 4 + 1][c]);
    o.z = f2bf(tile[tx * 4 + 2][c]);
    o.w = f2bf(tile[tx * 4 + 3][c]);
    *(ushort4*)&out[(size_t)(c0 + c) * R + r0 + tx * 4] = o;
  }
}

// ---------------- GEMM1: 128x128(panel) tile, 4 waves 64x64, 2-phase dbuf ----------------
// grid: 4096 blocks 1-D, XCD swizzle, mt FAST (concurrent blocks share B panel in L2).
// nid = e*256 + nt*16 + mt ; n0f = nt*64 (64 f-cols, interleaved up/gate 128-row panel).
__global__ __launch_bounds__(256, 4) void gemm1_kernel(
    const unsigned short* __restrict__ xb, const unsigned short* __restrict__ winT,
    const float* __restrict__ b_in, const int* __restrict__ offsets,
    const int* __restrict__ tok_list, unsigned short* __restrict__ act) {
  __shared__ unsigned short ldsA[2][128 * BK];
  __shared__ unsigned short ldsB[2][128 * BK];
  const int lin = blockIdx.x;
  const int nid = (lin & 7) * 512 + (lin >> 3);
  const int e  = nid >> 8;
  const int nt = (nid >> 4) & 15;
  const int mt = nid & 15;
  const int base = offsets[e];
  const int cnt = offsets[e + 1] - base;
  if (mt * 128 >= cnt) return;
  const int n0 = nt * 64;
  const int tid = threadIdx.x, w = tid >> 6, lane = tid & 63;

  const int srow0 = w * 32 + (lane >> 2);
  const int srow1 = srow0 + 16;
  const int t0 = tok_list[base + imin(mt * 128 + srow0, cnt - 1)];
  const int t1 = tok_list[base + imin(mt * 128 + srow1, cnt - 1)];
  const unsigned short* gA0 = xb + (size_t)t0 * H_DIM + (lane & 3) * 8;
  const unsigned short* gA1 = xb + (size_t)t1 * H_DIM + (lane & 3) * 8;
  auto nbmap = [&](int c) {
    int f = n0 + (c >> 5) * 16 + (c & 15);
    return ((c >> 4) & 1) ? (FF_DIM + f) : f;
  };
  const unsigned short* we = winT + (size_t)e * 2 * FF_DIM * H_DIM;
  const unsigned short* gB0 = we + (size_t)nbmap(srow0) * H_DIM + (lane & 3) * 8;
  const unsigned short* gB1 = we + (size_t)nbmap(srow1) * H_DIM + (lane & 3) * 8;

  f32x4 acc[4][4];
#pragma unroll
  for (int m = 0; m < 4; ++m)
#pragma unroll
    for (int n = 0; n < 4; ++n) acc[m][n] = (f32x4){0.f, 0.f, 0.f, 0.f};

#define STAGE1(buf, k0)                                        \
  do {                                                         \
    gload16(gA0 + (k0), &ldsA[buf][(w * 32 + 0) * BK]);        \
    gload16(gA1 + (k0), &ldsA[buf][(w * 32 + 16) * BK]);       \
    gload16(gB0 + (k0), &ldsB[buf][(w * 32 + 0) * BK]);        \
    gload16(gB1 + (k0), &ldsB[buf][(w * 32 + 16) * BK]);       \
  } while (0)

  STAGE1(0, 0);
  __syncthreads();
  int buf = 0;
  const int ko = (lane >> 4) * 8;
  const int wm = (w >> 1) * 64, wn = (w & 1) * 64;
  for (int kt = 0; kt < NT; ++kt) {
    if (kt + 1 < NT) STAGE1(buf ^ 1, (kt + 1) * BK);
    bf16x8 a[4], b[4];
#pragma unroll
    for (int mf = 0; mf < 4; ++mf)
      a[mf] = *(const bf16x8*)&ldsA[buf][(wm + mf * 16 + (lane & 15)) * BK + ko];
#pragma unroll
    for (int nf = 0; nf < 4; ++nf)
      b[nf] = *(const bf16x8*)&ldsB[buf][(wn + nf * 16 + (lane & 15)) * BK + ko];
#pragma unroll
    for (int mf = 0; mf < 4; ++mf)
#pragma unroll
      for (int nf = 0; nf < 4; ++nf)
        acc[mf][nf] = __builtin_amdgcn_mfma_f32_16x16x32_bf16(a[mf], b[nf], acc[mf][nf], 0, 0, 0);
    __syncthreads();
    buf ^= 1;
  }

  const float* bin = b_in + (size_t)e * 2 * FF_DIM;
#pragma unroll
  for (int mf = 0; mf < 4; ++mf) {
    int rbase = wm + mf * 16 + (lane >> 4) * 4;
#pragma unroll
    for (int p = 0; p < 2; ++p) {
      int f = n0 + (wn >> 1) + p * 16 + (lane & 15);
      float bu = bin[f], bg = bin[FF_DIM + f];
#pragma unroll
      for (int i = 0; i < 4; ++i) {
        int mrow = mt * 128 + rbase + i;
        if (mrow < cnt) {
          float up = acc[mf][2 * p][i] + bu;
          float gt = acc[mf][2 * p + 1][i] + bg;
          up = fminf(fmaxf(up, -CLIPV), CLIPV);
          gt = fminf(fmaxf(gt, -CLIPV), CLIPV);
          float av = (gt / (1.f + expf(-gt))) * up;
          act[(size_t)(base + mrow) * FF_DIM + f] = f2bf(av);
        }
      }
    }
  }
}

// ---------------- GEMM2: eo[slot] = act[slot]@W_out^T + b_out, 128x128, 2-phase ----------
// grid: 2048 blocks 1-D, XCD swizzle, mt FAST. nid = e*128 + nt*16 + mt ; n0 = nt*128.
__global__ __launch_bounds__(256, 4) void gemm2_kernel(
    const unsigned short* __restrict__ act, const unsigned short* __restrict__ woutT,
    const float* __restrict__ b_out, const int* __restrict__ offsets,
    float* __restrict__ eo) {
  __shared__ unsigned short ldsA[2][128 * BK];
  __shared__ unsigned short ldsB[2][128 * BK];
  const int lin = blockIdx.x;
  const int nid = (lin & 7) * 256 + (lin >> 3);
  const int e = nid >> 7;
  const int nt = (nid >> 4) & 7;
  const int mt = nid & 15;
  const int base = offsets[e];
  const int cnt = offsets[e + 1] - base;
  if (mt * 128 >= cnt) return;
  const int n0 = nt * 128;
  const int tid = threadIdx.x, w = tid >> 6, lane = tid & 63;

  const int srow0 = w * 32 + (lane >> 2);
  const int srow1 = srow0 + 16;
  const int m0_ = imin(mt * 128 + srow0, cnt - 1);
  const int m1_ = imin(mt * 128 + srow1, cnt - 1);
  const unsigned short* gA0 = act + (size_t)(base + m0_) * FF_DIM + (lane & 3) * 8;
  const unsigned short* gA1 = act + (size_t)(base + m1_) * FF_DIM + (lane & 3) * 8;
  const unsigned short* we = woutT + (size_t)e * H_DIM * FF_DIM;
  const unsigned short* gB0 = we + (size_t)(n0 + srow0) * FF_DIM + (lane & 3) * 8;
  const unsigned short* gB1 = we + (size_t)(n0 + srow1) * FF_DIM + (lane & 3) * 8;

  f32x4 acc[4][4];
#pragma unroll
  for (int m = 0; m < 4; ++m)
#pragma unroll
    for (int n = 0; n < 4; ++n) acc[m][n] = (f32x4){0.f, 0.f, 0.f, 0.f};

#define STAGE2(buf, k0)                                        \
  do {                                                         \
    gload16(gA0 + (k0), &ldsA[buf][(w * 32 + 0) * BK]);        \
    gload16(gA1 + (k0), &ldsA[buf][(w * 32 + 16) * BK]);       \
    gload16(gB0 + (k0), &ldsB[buf][(w * 32 + 0) * BK]);        \
    gload16(gB1 + (k0), &ldsB[buf][(w * 32 + 16) * BK]);       \
  } while (0)

  STAGE2(0, 0);
  __syncthreads();
  int buf = 0;
  const int ko = (lane >> 4) * 8;
  const int wm = (w >> 1) * 64, wn = (w & 1) * 64;
  for (int kt = 0; kt < FF_DIM / BK; ++kt) {
    if (kt + 1 < FF_DIM / BK) STAGE2(buf ^ 1, (kt + 1) * BK);
    bf16x8 a[4], b[4];
#pragma unroll
    for (int mf = 0; mf < 4; ++mf)
      a[mf] = *(const bf16x8*)&ldsA[buf][(wm + mf * 16 + (lane & 15)) * BK + ko];
#pragma unroll
    for (int nf = 0; nf < 4; ++nf)
      b[nf] = *(const bf16x8*)&ldsB[buf][(wn + nf * 16 + (lane & 15)) * BK + ko];
#pragma unroll
    for (int mf = 0; mf < 4; ++mf)
#pragma unroll
      for (int nf = 0; nf < 4; ++nf)
        acc[mf][nf] = __builtin_amdgcn_mfma_f32_16x16x32_bf16(a[mf], b[nf], acc[mf][nf], 0, 0, 0);
    __syncthreads();
    buf ^= 1;
  }

  const float* bo = b_out + (size_t)e * H_DIM;
#pragma unroll
  for (int mf = 0; mf < 4; ++mf) {
#pragma unroll
    for (int i = 0; i < 4; ++i) {
      int mrow = mt * 128 + wm + mf * 16 + (lane >> 4) * 4 + i;
      if (mrow < cnt) {
        float* row = eo + (size_t)(base + mrow) * H_DIM;
#pragma unroll
        for (int nf = 0; nf < 4; ++nf) {
          int h = n0 + wn + nf * 16 + (lane & 15);
          row[h] = acc[mf][nf][i] + bo[h];
        }
      }
    }
  }
}

// ---------------- combine: out[t] = sum_k topk_w[t][k] * eo[slot_of[t][k]] ----------------
__global__ __launch_bounds__(256) void combine_kernel(
    const float* __restrict__ eo, const float* __restrict__ topk_w,
    const int* __restrict__ slot_of, float* __restrict__ out) {
  int t = blockIdx.x;
  int tid = threadIdx.x;
  float4 r = make_float4(0.f, 0.f, 0.f, 0.f);
#pragma unroll
  for (int k = 0; k < TOPK; ++k) {
    int s = slot_of[t * TOPK + k];
    float wv = topk_w[t * TOPK + k];
    float4 v = ((const float4*)(eo + (size_t)s * H_DIM))[tid];
    r.x = fmaf(wv, v.x, r.x);
    r.y = fmaf(wv, v.y, r.y);
    r.z = fmaf(wv, v.z, r.z);
    r.w = fmaf(wv, v.w, r.w);
  }
  ((float4*)(out + (size_t)t * H_DIM))[tid] = r;
}

// ---------------- aux loss finalize ----------------
__global__ void finalize_kernel(const float* __restrict__ imp, const int* __restrict__ pos_cnt,
                                float* __restrict__ out_aux) {
  if (threadIdx.x == 0) {
    float s = 0.f;
    for (int p = 0; p < TOPK; ++p)
      s += (imp[p] / (float)S_TOK) * ((float)pos_cnt[p] / (float)S_TOK);
    *out_aux = AUXC * (float)E_NUM * s;
  }
}

extern "C" void kernel_launch(void* const* d_in, const int* in_sizes, int n_in,
                              void* d_out, int out_size, void* d_ws, size_t ws_size,
                              hipStream_t stream) {
  const float* x     = (const float*)d_in[0];
  const float* W_in  = (const float*)d_in[1];
  const float* b_in  = (const float*)d_in[2];
  const float* W_out = (const float*)d_in[3];
  const float* b_out = (const float*)d_in[4];
  const float* rw    = (const float*)d_in[5];
  const float* rb    = (const float*)d_in[6];
  float* out = (float*)d_out;

  char* ws = (char*)d_ws;
  size_t off = 0;
  auto alloc = [&](size_t bytes) {
    void* p = ws + off;
    off = (off + bytes + 255) & ~(size_t)255;
    return p;
  };
  unsigned short* xb    = (unsigned short*)alloc((size_t)S_TOK * H_DIM * 2);
  unsigned short* winT  = (unsigned short*)alloc((size_t)E_NUM * 2 * FF_DIM * H_DIM * 2);
  unsigned short* woutT = (unsigned short*)alloc((size_t)E_NUM * H_DIM * FF_DIM * 2);
  unsigned short* act   = (unsigned short*)alloc((size_t)S_TOK * TOPK * FF_DIM * 2);
  float* eo      = (float*)alloc((size_t)S_TOK * TOPK * H_DIM * 4);
  float* logits  = (float*)alloc((size_t)S_TOK * E_NUM * 4);
  int*   topk_i  = (int*)alloc(S_TOK * TOPK * 4);
  float* topk_w  = (float*)alloc(S_TOK * TOPK * 4);
  int*   tok_list= (int*)alloc(S_TOK * TOPK * 4);
  int*   slot_of = (int*)alloc(S_TOK * TOPK * 4);
  int* ctrl = (int*)alloc(64 * 4);
  int* counts = ctrl;
  int* cursor = ctrl + 16;
  int* pos_cnt = ctrl + 32;
  float* imp = (float*)(ctrl + 48);
  int* offsets = (int*)alloc(32 * 4);

  hipMemsetAsync(ctrl, 0, 64 * 4, stream);

  logits_kernel<<<S_TOK / 4, 256, 0, stream>>>(x, rw, rb, logits, xb);
  transpose_kernel<<<dim3(2 * FF_DIM / 64, H_DIM / 64, E_NUM), 256, 0, stream>>>(W_in, winT, H_DIM, 2 * FF_DIM);
  transpose_kernel<<<dim3(H_DIM / 64, FF_DIM / 64, E_NUM), 256, 0, stream>>>(W_out, woutT, FF_DIM, H_DIM);
  topk_kernel<<<S_TOK / 256, 256, 0, stream>>>(logits, topk_i, topk_w, counts, imp, pos_cnt);
  scan_kernel<<<1, 64, 0, stream>>>(counts, offsets);
  assign_kernel<<<S_TOK / 256, 256, 0, stream>>>(topk_i, offsets, cursor, tok_list, slot_of);
  gemm1_kernel<<<4096, 256, 0, stream>>>(xb, winT, b_in, offsets, tok_list, act);
  gemm2_kernel<<<2048, 256, 0, stream>>>(act, woutT, b_out, offsets, eo);
  combine_kernel<<<S_TOK, 256, 0, stream>>>(eo, topk_w, slot_of, out);
  finalize_kernel<<<1, 64, 0, stream>>>(imp, pos_cnt, out + (size_t)S_TOK * H_DIM);
}